// Round 18
// baseline (874.324 us; speedup 1.0000x reference)
//
#include <hip/hip_runtime.h>
#include <hip/hip_cooperative_groups.h>
#include <hip/hip_bf16.h>
#include <math.h>

namespace cg = cooperative_groups;

#define N_NODES 50000
#define N_EDGES 500000
#define H_DIM   128
#define BN_EPS  1e-5f
#define NTHR    256
#define GEMM_TILES ((N_NODES + 31) / 32)    // 1563
#define SCAN_NBLK  ((N_NODES + 255) / 256)  // 196
#define RED_NBLK   64

typedef __attribute__((ext_vector_type(8))) short short8;
typedef __attribute__((ext_vector_type(4))) float floatx4;

__device__ __forceinline__ ushort f2bf(float x)   // fp32 -> bf16 RNE
{
    unsigned u = __float_as_uint(x);
    unsigned r = (u + 0x7FFFu + ((u >> 16) & 1u)) >> 16;
    return (ushort)r;
}

// ===========================================================================
// Phase bodies as __device__ functions — shared between the cooperative mega
// kernel and the multi-dispatch fallback (one source of truth).
// All grid-strided: correct for ANY grid size.
// ===========================================================================

__device__ __forceinline__ void phase_zero_cvt(
    const float* __restrict__ W, ushort* __restrict__ wt, int* __restrict__ deg)
{
    int gid = blockIdx.x * NTHR + threadIdx.x;
    int gsz = gridDim.x * NTHR;
    for (int i = gid; i < N_NODES; i += gsz) deg[i] = 0;
    for (int i = gid; i < H_DIM * H_DIM; i += gsz) {
        int k = i >> 7, c = i & 127;
        wt[c * 128 + k] = f2bf(W[i]);
    }
}

__device__ __forceinline__ void phase_hist(
    const int* __restrict__ dst, int* __restrict__ deg)
{
    int gid = blockIdx.x * NTHR + threadIdx.x;
    int gsz = gridDim.x * NTHR;
    for (int e = gid; e < N_EDGES; e += gsz)
        atomicAdd(&deg[dst[e]], 1);
}

__device__ __forceinline__ void phase_scan_chunks(
    const int* __restrict__ deg, int* __restrict__ blocksum, int* red_i)
{
    int t = threadIdx.x;
    for (int chunk = blockIdx.x; chunk < SCAN_NBLK; chunk += gridDim.x) {
        __syncthreads();
        int i = chunk * 256 + t;
        red_i[t] = (i < N_NODES) ? deg[i] : 0;
        __syncthreads();
        #pragma unroll
        for (int off = 128; off; off >>= 1) {
            if (t < off) red_i[t] += red_i[t + off];
            __syncthreads();
        }
        if (t == 0) blocksum[chunk] = red_i[0];
    }
}

__device__ __forceinline__ void phase_scan_offsets(
    const int* __restrict__ blocksum, int* __restrict__ blockoff, int* red_i)
{
    if (blockIdx.x != 0) return;
    int t = threadIdx.x;
    red_i[t] = (t < SCAN_NBLK) ? blocksum[t] : 0;
    __syncthreads();
    for (int off = 1; off < 256; off <<= 1) {
        int u = (t >= off) ? red_i[t - off] : 0;
        __syncthreads();
        red_i[t] += u;
        __syncthreads();
    }
    if (t < SCAN_NBLK) blockoff[t] = (t == 0) ? 0 : red_i[t - 1];
}

__device__ __forceinline__ void phase_scan_final(
    const int* __restrict__ deg, const int* __restrict__ blockoff,
    int* __restrict__ rowptr, int* __restrict__ cursor, int* red_i)
{
    int t = threadIdx.x;
    for (int chunk = blockIdx.x; chunk < SCAN_NBLK; chunk += gridDim.x) {
        __syncthreads();
        int i = chunk * 256 + t;
        int v = (i < N_NODES) ? deg[i] : 0;
        red_i[t] = v;
        __syncthreads();
        for (int off = 1; off < 256; off <<= 1) {
            int u = (t >= off) ? red_i[t - off] : 0;
            __syncthreads();
            red_i[t] += u;
            __syncthreads();
        }
        int excl = red_i[t] - v + blockoff[chunk];
        if (i < N_NODES) {
            rowptr[i] = excl;
            cursor[i] = excl;
            if (i == N_NODES - 1) rowptr[N_NODES] = excl + v;
        }
    }
}

__device__ __forceinline__ void phase_scatter(
    const int* __restrict__ src, const int* __restrict__ dst,
    int* __restrict__ cursor, int* __restrict__ csr_src)
{
    int gid = blockIdx.x * NTHR + threadIdx.x;
    int gsz = gridDim.x * NTHR;
    for (int e = gid; e < N_EDGES; e += gsz) {
        int pos = atomicAdd(&cursor[dst[e]], 1);
        csr_src[pos] = src[e];
    }
}

// per-node dot + online softmax + aggregate -> bf16 neigh (masked-batch tail)
__device__ __forceinline__ void phase_agg(
    const float* __restrict__ emb, const int* __restrict__ rowptr,
    const int* __restrict__ csr_src, ushort* __restrict__ neigh_bf)
{
    int grp  = threadIdx.x >> 5;
    int lane = threadIdx.x & 31;
    for (int node = blockIdx.x * 8 + grp; node < N_NODES; node += gridDim.x * 8) {
        int beg = rowptr[node];
        int end = rowptr[node + 1];
        const float4 b = *((const float4*)(emb + (size_t)node * H_DIM) + lane);

        float m = -INFINITY;
        float denom = 0.f;
        float4 acc = {0.f, 0.f, 0.f, 0.f};

        for (int e = beg; e < end; e += 4) {
            int nrem = end - e;                   // >= 1
            float4 a[4];
            float  p[4];
            #pragma unroll
            for (int u = 0; u < 4; ++u) {
                int idx = (u < nrem) ? e + u : end - 1;   // clamp (masked)
                int s = csr_src[idx];
                a[u] = *((const float4*)(emb + (size_t)s * H_DIM) + lane);
            }
            #pragma unroll
            for (int u = 0; u < 4; ++u)
                p[u] = a[u].x * b.x + a[u].y * b.y + a[u].z * b.z + a[u].w * b.w;
            #pragma unroll
            for (int off = 16; off; off >>= 1) {
                #pragma unroll
                for (int u = 0; u < 4; ++u)
                    p[u] += __shfl_xor(p[u], off);
            }
            float mn = m;
            #pragma unroll
            for (int u = 0; u < 4; ++u)
                mn = fmaxf(mn, (u < nrem) ? p[u] : -INFINITY);
            float corr = __expf(m - mn);          // first iter: exp(-inf)=0
            float w[4];
            #pragma unroll
            for (int u = 0; u < 4; ++u)
                w[u] = (u < nrem) ? __expf(p[u] - mn) : 0.f;
            denom = denom * corr + w[0] + w[1] + w[2] + w[3];
            acc.x = acc.x * corr + a[0].x*w[0] + a[1].x*w[1] + a[2].x*w[2] + a[3].x*w[3];
            acc.y = acc.y * corr + a[0].y*w[0] + a[1].y*w[1] + a[2].y*w[2] + a[3].y*w[3];
            acc.z = acc.z * corr + a[0].z*w[0] + a[1].z*w[1] + a[2].z*w[2] + a[3].z*w[3];
            acc.w = acc.w * corr + a[0].w*w[0] + a[1].w*w[1] + a[2].w*w[2] + a[3].w*w[3];
            m = mn;
        }

        float inv = (end > beg) ? (1.0f / denom) : 0.f;
        unsigned lo = (unsigned)f2bf(acc.x * inv) | ((unsigned)f2bf(acc.y * inv) << 16);
        unsigned hi = (unsigned)f2bf(acc.z * inv) | ((unsigned)f2bf(acc.w * inv) << 16);
        uint2 pk; pk.x = lo; pk.y = hi;
        *((uint2*)(neigh_bf + (size_t)node * H_DIM) + lane) = pk;
    }
}

// LDS-free MFMA GEMM + column partials (r16-proven)
__device__ __forceinline__ void phase_gemm(
    const ushort* __restrict__ neigh_bf, const ushort* __restrict__ wt,
    float* __restrict__ h, float* __restrict__ partial,
    float* red_s, float* red_q)
{
    int t      = threadIdx.x;
    int w      = t >> 6;
    int lane64 = t & 63;
    int rbase  = (w >> 1) * 16;
    int c0     = (w & 1) * 64;
    int l15    = lane64 & 15;
    int kgrp   = lane64 >> 4;
    int k0l    = kgrp * 8;
    int contrib = (w >> 1) * 4 + kgrp;

    for (int tile = blockIdx.x; tile < GEMM_TILES; tile += gridDim.x) {
        __syncthreads();               // protect red_s/red_q reuse
        int r0   = tile * 32;
        int grow = r0 + rbase + l15;

        floatx4 acc4[4] = {{0.f,0.f,0.f,0.f},{0.f,0.f,0.f,0.f},
                           {0.f,0.f,0.f,0.f},{0.f,0.f,0.f,0.f}};
        #pragma unroll
        for (int ks = 0; ks < 4; ++ks) {
            int k0 = ks * 32 + k0l;
            short8 af = {0,0,0,0,0,0,0,0};
            if (grow < N_NODES)
                af = *(const short8*)(neigh_bf + (size_t)grow * H_DIM + k0);
            #pragma unroll
            for (int ct = 0; ct < 4; ++ct) {
                int col = c0 + ct * 16 + l15;
                short8 bf = *(const short8*)(wt + (size_t)col * 128 + k0);
                acc4[ct] = __builtin_amdgcn_mfma_f32_16x16x32_bf16(af, bf, acc4[ct], 0, 0, 0);
            }
        }

        #pragma unroll
        for (int ct = 0; ct < 4; ++ct) {
            int col = c0 + ct * 16 + l15;
            float ps = 0.f, pq = 0.f;
            #pragma unroll
            for (int reg = 0; reg < 4; ++reg) {
                float v = acc4[ct][reg];
                int gr = r0 + rbase + kgrp * 4 + reg;
                if (gr < N_NODES) h[(size_t)gr * H_DIM + col] = v;
                ps += v;
                pq += v * v;
            }
            red_s[col * 9 + contrib] = ps;
            red_q[col * 9 + contrib] = pq;
        }
        __syncthreads();

        float s = 0.f;
        if (t < 128) {
            #pragma unroll
            for (int q = 0; q < 8; ++q) s += red_s[t * 9 + q];
        } else {
            #pragma unroll
            for (int q = 0; q < 8; ++q) s += red_q[(t - 128) * 9 + q];
        }
        partial[(size_t)tile * 256 + t] = s;
    }
}

__device__ __forceinline__ void phase_reduce(
    const float* __restrict__ partial, float* __restrict__ partial2)
{
    int t = threadIdx.x;
    for (int g = blockIdx.x; g < RED_NBLK; g += gridDim.x) {
        float s = 0.f;
        for (int b = g; b < GEMM_TILES; b += RED_NBLK)
            s += partial[(size_t)b * 256 + t];
        partial2[(size_t)g * 256 + t] = s;
    }
}

__device__ __forceinline__ void phase_bn_tanh(
    const float* __restrict__ partial2, const float* __restrict__ gamma,
    const float* __restrict__ beta, float* __restrict__ h,
    float* tot, float* sc_s, float* sh_s)
{
    int t = threadIdx.x;
    float s = 0.f;
    #pragma unroll 8
    for (int b = 0; b < RED_NBLK; ++b)
        s += partial2[b * 256 + t];        // coalesced, L2-hot
    tot[t] = s;
    __syncthreads();
    if (t < 128) {
        float cs = tot[t];
        float cq = tot[t + 128];
        const float invN = 1.0f / (float)N_NODES;
        float mu  = cs * invN;
        float var = cq * invN - mu * mu;   // biased, matches jnp.var
        float sc  = gamma[t] * rsqrtf(var + BN_EPS);
        sc_s[t] = sc;
        sh_s[t] = beta[t] - mu * sc;
    }
    __syncthreads();

    const size_t total4 = (size_t)N_NODES * H_DIM / 4;
    size_t gsz = (size_t)gridDim.x * NTHR;
    for (size_t i = (size_t)blockIdx.x * NTHR + t; i < total4; i += gsz) {
        size_t idx4 = i * 4;
        int c = (int)(idx4 & (H_DIM - 1));
        float4 v = *(float4*)(h + idx4);
        v.x = tanhf(v.x * sc_s[c + 0] + sh_s[c + 0]);
        v.y = tanhf(v.y * sc_s[c + 1] + sh_s[c + 1]);
        v.z = tanhf(v.z * sc_s[c + 2] + sh_s[c + 2]);
        v.w = tanhf(v.w * sc_s[c + 3] + sh_s[c + 3]);
        *(float4*)(h + idx4) = v;
    }
}

// ===========================================================================
// Cooperative mega kernel: all phases, grid.sync between. Grid size comes
// from the runtime occupancy query (r17's hard-coded 1024 was rejected).
// ===========================================================================
__global__ void mega_kernel(
    const float* __restrict__ emb, const float* __restrict__ W,
    const float* __restrict__ gamma, const float* __restrict__ beta,
    const int* __restrict__ src, const int* __restrict__ dst,
    float* __restrict__ out,
    int* __restrict__ deg, int* __restrict__ rowptr, int* __restrict__ cursor,
    int* __restrict__ csr_src, int* __restrict__ blocksum,
    int* __restrict__ blockoff, float* __restrict__ partial,
    float* __restrict__ partial2, ushort* __restrict__ wt,
    ushort* __restrict__ neigh_bf)
{
    cg::grid_group grid = cg::this_grid();
    __shared__ int   red_i[256];
    __shared__ float red_s[128 * 9];
    __shared__ float red_q[128 * 9];
    __shared__ float sc_s[128];
    __shared__ float sh_s[128];

    phase_zero_cvt(W, wt, deg);                          grid.sync();
    phase_hist(dst, deg);                                grid.sync();
    phase_scan_chunks(deg, blocksum, red_i);             grid.sync();
    phase_scan_offsets(blocksum, blockoff, red_i);       grid.sync();
    phase_scan_final(deg, blockoff, rowptr, cursor, red_i); grid.sync();
    phase_scatter(src, dst, cursor, csr_src);            grid.sync();
    phase_agg(emb, rowptr, csr_src, neigh_bf);           grid.sync();
    phase_gemm(neigh_bf, wt, out, partial, red_s, red_q); grid.sync();
    phase_reduce(partial, partial2);                     grid.sync();
    phase_bn_tanh(partial2, gamma, beta, out, red_s, sc_s, sh_s);
}

// ===========================================================================
// Fallback wrappers (multi-dispatch, r16-equivalent) — used when cooperative
// launch is unsupported.
// ===========================================================================
__global__ __launch_bounds__(256) void k_zero_cvt(const float* W, ushort* wt, int* deg)
{ phase_zero_cvt(W, wt, deg); }
__global__ __launch_bounds__(256) void k_hist(const int* dst, int* deg)
{ phase_hist(dst, deg); }
__global__ __launch_bounds__(256) void k_scan_chunks(const int* deg, int* blocksum)
{ __shared__ int red_i[256]; phase_scan_chunks(deg, blocksum, red_i); }
__global__ __launch_bounds__(256) void k_scan_offsets(const int* blocksum, int* blockoff)
{ __shared__ int red_i[256]; phase_scan_offsets(blocksum, blockoff, red_i); }
__global__ __launch_bounds__(256) void k_scan_final(const int* deg, const int* blockoff, int* rowptr, int* cursor)
{ __shared__ int red_i[256]; phase_scan_final(deg, blockoff, rowptr, cursor, red_i); }
__global__ __launch_bounds__(256) void k_scatter(const int* src, const int* dst, int* cursor, int* csr_src)
{ phase_scatter(src, dst, cursor, csr_src); }
__global__ __launch_bounds__(256) void k_agg(const float* emb, const int* rowptr, const int* csr_src, ushort* neigh_bf)
{ phase_agg(emb, rowptr, csr_src, neigh_bf); }
__global__ __launch_bounds__(256) void k_gemm(const ushort* neigh_bf, const ushort* wt, float* h, float* partial)
{ __shared__ float red_s[128*9]; __shared__ float red_q[128*9];
  phase_gemm(neigh_bf, wt, h, partial, red_s, red_q); }
__global__ __launch_bounds__(256) void k_reduce(const float* partial, float* partial2)
{ phase_reduce(partial, partial2); }
__global__ __launch_bounds__(256) void k_bn_tanh(const float* partial2, const float* gamma, const float* beta, float* h)
{ __shared__ float tot[256]; __shared__ float sc_s[128]; __shared__ float sh_s[128];
  phase_bn_tanh(partial2, gamma, beta, h, tot, sc_s, sh_s); }

// ---------------------------------------------------------------------------
extern "C" void kernel_launch(void* const* d_in, const int* in_sizes, int n_in,
                              void* d_out, int out_size, void* d_ws, size_t ws_size,
                              hipStream_t stream)
{
    const float* ent_emb = (const float*)d_in[0];
    const float* neigh_w = (const float*)d_in[1];
    const float* gamma   = (const float*)d_in[2];
    const float* beta    = (const float*)d_in[3];
    const int*   src     = (const int*)d_in[4];
    const int*   dst     = (const int*)d_in[5];
    float* out = (float*)d_out;

    int*    deg      = (int*)d_ws;                                   // 50000
    int*    rowptr   = deg + N_NODES;                                // 50001
    int*    cursor   = rowptr + N_NODES + 1;                         // 50000
    int*    csr_src  = cursor + N_NODES;                             // 500000
    int*    blocksum = csr_src + N_EDGES;                            // 196
    int*    blockoff = blocksum + SCAN_NBLK;                         // 196
    float*  partial  = (float*)(blockoff + SCAN_NBLK);               // 1563*256
    float*  partial2 = partial + (size_t)GEMM_TILES * 256;           // 64*256
    ushort* wt       = (ushort*)(partial2 + (size_t)RED_NBLK * 256); // 16384
    ushort* neigh_bf = wt + H_DIM * H_DIM;                           // 6.4M

    // Host-side queries: run at graph-capture time only (free in replay).
    int dev = 0;
    hipGetDevice(&dev);
    hipDeviceProp_t prop;
    hipGetDeviceProperties(&prop, dev);
    int maxB = 0;
    hipOccupancyMaxActiveBlocksPerMultiprocessor(&maxB, (const void*)mega_kernel,
                                                 NTHR, 0);
    bool coop = (prop.cooperativeLaunch != 0) && (maxB > 0);

    if (coop) {
        int nblk = maxB * prop.multiProcessorCount;
        if (nblk > 2048) nblk = 2048;
        void* kargs[] = {
            (void*)&ent_emb, (void*)&neigh_w, (void*)&gamma, (void*)&beta,
            (void*)&src, (void*)&dst, (void*)&out,
            (void*)&deg, (void*)&rowptr, (void*)&cursor, (void*)&csr_src,
            (void*)&blocksum, (void*)&blockoff, (void*)&partial, (void*)&partial2,
            (void*)&wt, (void*)&neigh_bf
        };
        hipError_t err = hipLaunchCooperativeKernel((const void*)mega_kernel,
                                                    dim3(nblk), dim3(NTHR),
                                                    kargs, 0, stream);
        if (err == hipSuccess) return;
        // fall through to multi-dispatch on failure
    }

    // ---- fallback: proven multi-dispatch pipeline (r16 ~150us) ----
    k_zero_cvt<<<256, NTHR, 0, stream>>>(neigh_w, wt, deg);
    k_hist<<<(N_EDGES + NTHR - 1) / NTHR, NTHR, 0, stream>>>(dst, deg);
    k_scan_chunks<<<SCAN_NBLK, NTHR, 0, stream>>>(deg, blocksum);
    k_scan_offsets<<<1, NTHR, 0, stream>>>(blocksum, blockoff);
    k_scan_final<<<SCAN_NBLK, NTHR, 0, stream>>>(deg, blockoff, rowptr, cursor);
    k_scatter<<<(N_EDGES + NTHR - 1) / NTHR, NTHR, 0, stream>>>(src, dst, cursor, csr_src);
    k_agg<<<(N_NODES + 7) / 8, NTHR, 0, stream>>>(ent_emb, rowptr, csr_src, neigh_bf);
    k_gemm<<<GEMM_TILES, NTHR, 0, stream>>>(neigh_bf, wt, out, partial);
    k_reduce<<<RED_NBLK, NTHR, 0, stream>>>(partial, partial2);
    k_bn_tanh<<<512, NTHR, 0, stream>>>(partial2, gamma, beta, out);
}

// Round 19
// 154.301 us; speedup vs baseline: 5.6663x; 5.6663x over previous
//
#include <hip/hip_runtime.h>
#include <hip/hip_bf16.h>
#include <math.h>

#define N_NODES 50000
#define N_EDGES 500000
#define H_DIM   128
#define BN_EPS  1e-5f
#define GEMM_GRID ((N_NODES + 31) / 32)     // 1563: 32 rows per block
#define SCAN_NBLK ((N_NODES + 255) / 256)   // 196
#define RED_NBLK  64                        // stage-1 partial-reduction blocks

typedef __attribute__((ext_vector_type(8))) short short8;
typedef __attribute__((ext_vector_type(4))) float floatx4;

__device__ __forceinline__ ushort f2bf(float x)   // fp32 -> bf16 RNE
{
    unsigned u = __float_as_uint(x);
    unsigned r = (u + 0x7FFFu + ((u >> 16) & 1u)) >> 16;
    return (ushort)r;
}

// ---------------------------------------------------------------------------
// K0: zero deg[] with a proper grid (hipMemsetAsync's tiny-grid fill kernel
// costs ~40us on first touch; a real grid is ~1.5us).
// ---------------------------------------------------------------------------
__global__ __launch_bounds__(256) void zero_deg_kernel(int* __restrict__ deg)
{
    int i = (blockIdx.x * 256 + threadIdx.x) * 4;
    if (i + 3 < N_NODES) {
        *(int4*)(deg + i) = make_int4(0, 0, 0, 0);
    } else {
        for (int k = i; k < N_NODES; ++k) deg[k] = 0;
    }
}

// ---------------------------------------------------------------------------
// K1: histogram of dst -> deg[]  (+ fused W fp32[k][c] -> bf16 wt[c][k])
// ---------------------------------------------------------------------------
__global__ __launch_bounds__(256) void hist_cvt_kernel(
    const int* __restrict__ dst, int* __restrict__ deg,
    const float* __restrict__ W, ushort* __restrict__ wt)
{
    int e = blockIdx.x * blockDim.x + threadIdx.x;
    if (e < N_EDGES) atomicAdd(&deg[dst[e]], 1);
    if (e < H_DIM * H_DIM) {
        int k = e >> 7, c = e & 127;
        wt[c * 128 + k] = f2bf(W[e]);
    }
}

// ---------------------------------------------------------------------------
// K2a: per-block sums of deg (196 blocks x 256)
// ---------------------------------------------------------------------------
__global__ __launch_bounds__(256) void scan_partial_kernel(
    const int* __restrict__ deg, int* __restrict__ blocksum)
{
    __shared__ int red[256];
    int t = threadIdx.x;
    int i = blockIdx.x * 256 + t;
    red[t] = (i < N_NODES) ? deg[i] : 0;
    __syncthreads();
    #pragma unroll
    for (int off = 128; off; off >>= 1) {
        if (t < off) red[t] += red[t + off];
        __syncthreads();
    }
    if (t == 0) blocksum[blockIdx.x] = red[0];
}

// ---------------------------------------------------------------------------
// K2b: every block scans the 196 block sums in LDS (redundant, cheap), then
// in-block exclusive scan of deg -> rowptr, cursor.
// ---------------------------------------------------------------------------
__global__ __launch_bounds__(256) void scan_final_kernel(
    const int* __restrict__ deg, const int* __restrict__ blocksum,
    int* __restrict__ rowptr, int* __restrict__ cursor)
{
    __shared__ int bs[256];
    __shared__ int s[256];
    int t = threadIdx.x;

    bs[t] = (t < SCAN_NBLK) ? blocksum[t] : 0;
    __syncthreads();
    for (int off = 1; off < 256; off <<= 1) {
        int v = (t >= off) ? bs[t - off] : 0;
        __syncthreads();
        bs[t] += v;
        __syncthreads();
    }
    int blockoff = (blockIdx.x == 0) ? 0 : bs[blockIdx.x - 1];

    int i = blockIdx.x * 256 + t;
    int v = (i < N_NODES) ? deg[i] : 0;
    s[t] = v;
    __syncthreads();
    for (int off = 1; off < 256; off <<= 1) {
        int u = (t >= off) ? s[t - off] : 0;
        __syncthreads();
        s[t] += u;
        __syncthreads();
    }
    int excl = s[t] - v + blockoff;
    if (i < N_NODES) {
        rowptr[i] = excl;
        cursor[i] = excl;
        if (i == N_NODES - 1) rowptr[N_NODES] = excl + v;
    }
}

// ---------------------------------------------------------------------------
// K3: scatter src ids into CSR slots (counting sort by dst)
// ---------------------------------------------------------------------------
__global__ __launch_bounds__(256) void csr_scatter_kernel(
    const int* __restrict__ src, const int* __restrict__ dst,
    int* __restrict__ cursor, int* __restrict__ csr_src)
{
    int e = blockIdx.x * blockDim.x + threadIdx.x;
    if (e >= N_EDGES) return;
    int pos = atomicAdd(&cursor[dst[e]], 1);
    csr_src[pos] = src[e];
}

// ---------------------------------------------------------------------------
// K4 v2: TWO independent nodes per 32-lane group, interleaved online-softmax
// streams -> 8 gather loads in flight across 2 dep-chains (r16 had one chain
// of 4; r9's 8-deep single chain blew registers instead). Per-node math and
// summation order identical to r16 -> absmax unchanged. Masked-batch tails
// (verified correct in r18's mega run, same absmax). bf16 output.
// ---------------------------------------------------------------------------
__global__ __launch_bounds__(256) void node_aggregate_kernel(
    const float* __restrict__ emb,
    const int* __restrict__ rowptr,
    const int* __restrict__ csr_src,
    ushort* __restrict__ neigh_bf)
{
    int pair = blockIdx.x * 8 + (threadIdx.x >> 5);   // 8 groups/block
    int lane = threadIdx.x & 31;
    int n0 = pair * 2;
    int n1 = n0 + 1;
    if (n0 >= N_NODES) return;
    bool has1 = (n1 < N_NODES);

    int beg0 = rowptr[n0], end0 = rowptr[n0 + 1];
    int beg1 = has1 ? rowptr[n1] : 0;
    int end1 = has1 ? rowptr[n1 + 1] : 0;

    const float4 b0 = *((const float4*)(emb + (size_t)n0 * H_DIM) + lane);
    const float4 b1 = has1 ? *((const float4*)(emb + (size_t)n1 * H_DIM) + lane)
                           : make_float4(0.f, 0.f, 0.f, 0.f);

    float  m0 = -INFINITY, m1 = -INFINITY;
    float  den0 = 0.f, den1 = 0.f;
    float4 acc0 = {0.f, 0.f, 0.f, 0.f};
    float4 acc1 = {0.f, 0.f, 0.f, 0.f};

    int e0 = beg0, e1 = beg1;
    while (e0 < end0 || e1 < end1) {
        int r0 = end0 - e0;               // may be <= 0 (stream done)
        int r1 = end1 - e1;
        float4 a0[4], a1[4];
        float  p0[4], p1[4];

        // issue both streams' loads first: up to 8 outstanding gathers
        if (r0 > 0) {
            #pragma unroll
            for (int u = 0; u < 4; ++u) {
                int idx = (u < r0) ? e0 + u : end0 - 1;   // clamp (masked)
                int s = csr_src[idx];
                a0[u] = *((const float4*)(emb + (size_t)s * H_DIM) + lane);
            }
        }
        if (r1 > 0) {
            #pragma unroll
            for (int u = 0; u < 4; ++u) {
                int idx = (u < r1) ? e1 + u : end1 - 1;
                int s = csr_src[idx];
                a1[u] = *((const float4*)(emb + (size_t)s * H_DIM) + lane);
            }
        }

        if (r0 > 0) {
            #pragma unroll
            for (int u = 0; u < 4; ++u)
                p0[u] = a0[u].x * b0.x + a0[u].y * b0.y + a0[u].z * b0.z + a0[u].w * b0.w;
            #pragma unroll
            for (int off = 16; off; off >>= 1) {
                #pragma unroll
                for (int u = 0; u < 4; ++u)
                    p0[u] += __shfl_xor(p0[u], off);
            }
            float mn = m0;
            #pragma unroll
            for (int u = 0; u < 4; ++u)
                mn = fmaxf(mn, (u < r0) ? p0[u] : -INFINITY);
            float corr = __expf(m0 - mn);
            float w[4];
            #pragma unroll
            for (int u = 0; u < 4; ++u)
                w[u] = (u < r0) ? __expf(p0[u] - mn) : 0.f;
            den0 = den0 * corr + w[0] + w[1] + w[2] + w[3];
            acc0.x = acc0.x * corr + a0[0].x*w[0] + a0[1].x*w[1] + a0[2].x*w[2] + a0[3].x*w[3];
            acc0.y = acc0.y * corr + a0[0].y*w[0] + a0[1].y*w[1] + a0[2].y*w[2] + a0[3].y*w[3];
            acc0.z = acc0.z * corr + a0[0].z*w[0] + a0[1].z*w[1] + a0[2].z*w[2] + a0[3].z*w[3];
            acc0.w = acc0.w * corr + a0[0].w*w[0] + a0[1].w*w[1] + a0[2].w*w[2] + a0[3].w*w[3];
            m0 = mn;
        }
        if (r1 > 0) {
            #pragma unroll
            for (int u = 0; u < 4; ++u)
                p1[u] = a1[u].x * b1.x + a1[u].y * b1.y + a1[u].z * b1.z + a1[u].w * b1.w;
            #pragma unroll
            for (int off = 16; off; off >>= 1) {
                #pragma unroll
                for (int u = 0; u < 4; ++u)
                    p1[u] += __shfl_xor(p1[u], off);
            }
            float mn = m1;
            #pragma unroll
            for (int u = 0; u < 4; ++u)
                mn = fmaxf(mn, (u < r1) ? p1[u] : -INFINITY);
            float corr = __expf(m1 - mn);
            float w[4];
            #pragma unroll
            for (int u = 0; u < 4; ++u)
                w[u] = (u < r1) ? __expf(p1[u] - mn) : 0.f;
            den1 = den1 * corr + w[0] + w[1] + w[2] + w[3];
            acc1.x = acc1.x * corr + a1[0].x*w[0] + a1[1].x*w[1] + a1[2].x*w[2] + a1[3].x*w[3];
            acc1.y = acc1.y * corr + a1[0].y*w[0] + a1[1].y*w[1] + a1[2].y*w[2] + a1[3].y*w[3];
            acc1.z = acc1.z * corr + a1[0].z*w[0] + a1[1].z*w[1] + a1[2].z*w[2] + a1[3].z*w[3];
            acc1.w = acc1.w * corr + a1[0].w*w[0] + a1[1].w*w[1] + a1[2].w*w[2] + a1[3].w*w[3];
            m1 = mn;
        }
        e0 += 4;
        e1 += 4;
    }

    {
        float inv = (end0 > beg0) ? (1.0f / den0) : 0.f;
        unsigned lo = (unsigned)f2bf(acc0.x * inv) | ((unsigned)f2bf(acc0.y * inv) << 16);
        unsigned hi = (unsigned)f2bf(acc0.z * inv) | ((unsigned)f2bf(acc0.w * inv) << 16);
        uint2 pk; pk.x = lo; pk.y = hi;
        *((uint2*)(neigh_bf + (size_t)n0 * H_DIM) + lane) = pk;
    }
    if (has1) {
        float inv = (end1 > beg1) ? (1.0f / den1) : 0.f;
        unsigned lo = (unsigned)f2bf(acc1.x * inv) | ((unsigned)f2bf(acc1.y * inv) << 16);
        unsigned hi = (unsigned)f2bf(acc1.z * inv) | ((unsigned)f2bf(acc1.w * inv) << 16);
        uint2 pk; pk.x = lo; pk.y = hi;
        *((uint2*)(neigh_bf + (size_t)n1 * H_DIM) + lane) = pk;
    }
}

// ---------------------------------------------------------------------------
// K5: h = neigh_bf @ W via MFMA, NO data LDS (r16-proven): A-fragments from
// global bf16 neigh, B-fragments from L2-hot wt. 9 KB stats LDS only.
// ---------------------------------------------------------------------------
__global__ __launch_bounds__(256) void gemm_stats_kernel(
    const ushort* __restrict__ neigh_bf,
    const ushort* __restrict__ wt,
    float* __restrict__ h,
    float* __restrict__ partial)
{
    __shared__ float red_s[128 * 9];
    __shared__ float red_q[128 * 9];

    int t  = threadIdx.x;
    int r0 = blockIdx.x * 32;

    int w      = t >> 6;
    int lane64 = t & 63;
    int rbase  = (w >> 1) * 16;
    int c0     = (w & 1) * 64;
    int l15    = lane64 & 15;
    int kgrp   = lane64 >> 4;
    int grow   = r0 + rbase + l15;
    int k0l    = kgrp * 8;

    floatx4 acc4[4] = {{0.f,0.f,0.f,0.f},{0.f,0.f,0.f,0.f},
                       {0.f,0.f,0.f,0.f},{0.f,0.f,0.f,0.f}};

    #pragma unroll
    for (int ks = 0; ks < 4; ++ks) {
        int k0 = ks * 32 + k0l;
        short8 af = {0,0,0,0,0,0,0,0};
        if (grow < N_NODES)
            af = *(const short8*)(neigh_bf + (size_t)grow * H_DIM + k0);
        #pragma unroll
        for (int ct = 0; ct < 4; ++ct) {
            int col = c0 + ct * 16 + l15;
            short8 bf = *(const short8*)(wt + (size_t)col * 128 + k0);
            acc4[ct] = __builtin_amdgcn_mfma_f32_16x16x32_bf16(af, bf, acc4[ct], 0, 0, 0);
        }
    }

    int contrib = (w >> 1) * 4 + kgrp;
    #pragma unroll
    for (int ct = 0; ct < 4; ++ct) {
        int col = c0 + ct * 16 + l15;
        float ps = 0.f, pq = 0.f;
        #pragma unroll
        for (int reg = 0; reg < 4; ++reg) {
            float v = acc4[ct][reg];
            int gr = r0 + rbase + kgrp * 4 + reg;
            if (gr < N_NODES) h[(size_t)gr * H_DIM + col] = v;
            ps += v;
            pq += v * v;
        }
        red_s[col * 9 + contrib] = ps;
        red_q[col * 9 + contrib] = pq;
    }
    __syncthreads();

    float s = 0.f;
    if (t < 128) {
        #pragma unroll
        for (int q = 0; q < 8; ++q) s += red_s[t * 9 + q];
    } else {
        #pragma unroll
        for (int q = 0; q < 8; ++q) s += red_q[(t - 128) * 9 + q];
    }
    partial[(size_t)blockIdx.x * 256 + t] = s;
}

// ---------------------------------------------------------------------------
// K6: stage-1 partial reduction: 64 blocks sum 1563 rows -> partial2[64][256]
// ---------------------------------------------------------------------------
__global__ __launch_bounds__(256) void reduce_partials_kernel(
    const float* __restrict__ partial, float* __restrict__ partial2)
{
    int t = threadIdx.x;
    int g = blockIdx.x;
    float s = 0.f;
    for (int b = g; b < GEMM_GRID; b += RED_NBLK)
        s += partial[(size_t)b * 256 + t];
    partial2[(size_t)g * 256 + t] = s;
}

// ---------------------------------------------------------------------------
// K7: each of 512 blocks redundantly folds the 64KB L2-hot partial2 into
// scale/shift in LDS, then grid-strides normalize+tanh over h in place.
// ---------------------------------------------------------------------------
__global__ __launch_bounds__(256) void bn_fold_tanh_kernel(
    const float* __restrict__ partial2,
    const float* __restrict__ gamma,
    const float* __restrict__ beta,
    float* __restrict__ h)
{
    __shared__ float tot[256];
    __shared__ float sc_s[128];
    __shared__ float sh_s[128];
    int t = threadIdx.x;

    float s = 0.f;
    #pragma unroll 8
    for (int b = 0; b < RED_NBLK; ++b)
        s += partial2[b * 256 + t];
    tot[t] = s;
    __syncthreads();
    if (t < 128) {
        float cs = tot[t];
        float cq = tot[t + 128];
        const float invN = 1.0f / (float)N_NODES;
        float mu  = cs * invN;
        float var = cq * invN - mu * mu;   // biased, matches jnp.var
        float sc  = gamma[t] * rsqrtf(var + BN_EPS);
        sc_s[t] = sc;
        sh_s[t] = beta[t] - mu * sc;
    }
    __syncthreads();

    const size_t total4 = (size_t)N_NODES * H_DIM / 4;
    for (size_t i = (size_t)blockIdx.x * 256 + t; i < total4;
         i += (size_t)gridDim.x * 256) {
        size_t idx4 = i * 4;
        int c = (int)(idx4 & (H_DIM - 1));
        float4 v = *(float4*)(h + idx4);
        v.x = tanhf(v.x * sc_s[c + 0] + sh_s[c + 0]);
        v.y = tanhf(v.y * sc_s[c + 1] + sh_s[c + 1]);
        v.z = tanhf(v.z * sc_s[c + 2] + sh_s[c + 2]);
        v.w = tanhf(v.w * sc_s[c + 3] + sh_s[c + 3]);
        *(float4*)(h + idx4) = v;
    }
}

// ---------------------------------------------------------------------------
extern "C" void kernel_launch(void* const* d_in, const int* in_sizes, int n_in,
                              void* d_out, int out_size, void* d_ws, size_t ws_size,
                              hipStream_t stream)
{
    const float* ent_emb = (const float*)d_in[0];
    const float* neigh_w = (const float*)d_in[1];
    const float* gamma   = (const float*)d_in[2];
    const float* beta    = (const float*)d_in[3];
    const int*   src     = (const int*)d_in[4];
    const int*   dst     = (const int*)d_in[5];
    float* out = (float*)d_out;

    int*    deg      = (int*)d_ws;                                   // 50000
    int*    rowptr   = deg + N_NODES;                                // 50001
    int*    cursor   = rowptr + N_NODES + 1;                         // 50000
    int*    csr_src  = cursor + N_NODES;                             // 500000
    int*    blocksum = csr_src + N_EDGES;                            // 196
    float*  partial  = (float*)(blocksum + SCAN_NBLK);               // 1563*256
    float*  partial2 = partial + (size_t)GEMM_GRID * 256;            // 64*256
    ushort* wt       = (ushort*)(partial2 + (size_t)RED_NBLK * 256); // 16384
    ushort* neigh_bf = wt + H_DIM * H_DIM;                           // 6.4M

    zero_deg_kernel<<<(N_NODES / 4 + 255) / 256, 256, 0, stream>>>(deg);

    // CSR build (counting sort by dst) + W->bf16^T fused into hist
    hist_cvt_kernel<<<(N_EDGES + 255) / 256, 256, 0, stream>>>(dst, deg, neigh_w, wt);
    scan_partial_kernel<<<SCAN_NBLK, 256, 0, stream>>>(deg, blocksum);
    scan_final_kernel<<<SCAN_NBLK, 256, 0, stream>>>(deg, blocksum, rowptr, cursor);
    csr_scatter_kernel<<<(N_EDGES + 255) / 256, 256, 0, stream>>>(src, dst, cursor, csr_src);

    // gather + online softmax + aggregate (2 interleaved nodes per group)
    node_aggregate_kernel<<<(N_NODES / 2 + 7) / 8, 256, 0, stream>>>(
        ent_emb, rowptr, csr_src, neigh_bf);

    // LDS-free MFMA GEMM: h = neigh_bf @ W + column partials
    gemm_stats_kernel<<<GEMM_GRID, 256, 0, stream>>>(neigh_bf, wt, out, partial);

    // hierarchical BN stats fold + normalize + tanh
    reduce_partials_kernel<<<RED_NBLK, 256, 0, stream>>>(partial, partial2);
    bn_fold_tanh_kernel<<<512, 256, 0, stream>>>(partial2, gamma, beta, out);
}

// Round 20
// 150.273 us; speedup vs baseline: 5.8182x; 1.0268x over previous
//
#include <hip/hip_runtime.h>
#include <hip/hip_bf16.h>
#include <math.h>

#define N_NODES 50000
#define N_EDGES 500000
#define H_DIM   128
#define BN_EPS  1e-5f
#define GEMM_GRID ((N_NODES + 31) / 32)     // 1563: 32 rows per block
#define SCAN_NBLK ((N_NODES + 255) / 256)   // 196
#define RED_NBLK  64                        // stage-1 partial-reduction blocks

typedef __attribute__((ext_vector_type(8))) short short8;
typedef __attribute__((ext_vector_type(4))) float floatx4;

__device__ __forceinline__ ushort f2bf(float x)   // fp32 -> bf16 RNE
{
    unsigned u = __float_as_uint(x);
    unsigned r = (u + 0x7FFFu + ((u >> 16) & 1u)) >> 16;
    return (ushort)r;
}

// ---------------------------------------------------------------------------
// K0: zero deg[] with a proper grid (hipMemsetAsync's tiny-grid fill kernel
// costs ~40us on first touch; a real grid is ~1.5us).
// ---------------------------------------------------------------------------
__global__ __launch_bounds__(256) void zero_deg_kernel(int* __restrict__ deg)
{
    int i = (blockIdx.x * 256 + threadIdx.x) * 4;
    if (i + 3 < N_NODES) {
        *(int4*)(deg + i) = make_int4(0, 0, 0, 0);
    } else {
        for (int k = i; k < N_NODES; ++k) deg[k] = 0;
    }
}

// ---------------------------------------------------------------------------
// K1: histogram of dst -> deg[]  (+ fused W fp32[k][c] -> bf16 wt[c][k])
// ---------------------------------------------------------------------------
__global__ __launch_bounds__(256) void hist_cvt_kernel(
    const int* __restrict__ dst, int* __restrict__ deg,
    const float* __restrict__ W, ushort* __restrict__ wt)
{
    int e = blockIdx.x * blockDim.x + threadIdx.x;
    if (e < N_EDGES) atomicAdd(&deg[dst[e]], 1);
    if (e < H_DIM * H_DIM) {
        int k = e >> 7, c = e & 127;
        wt[c * 128 + k] = f2bf(W[e]);
    }
}

// ---------------------------------------------------------------------------
// K2a: per-block sums of deg (196 blocks x 256)
// ---------------------------------------------------------------------------
__global__ __launch_bounds__(256) void scan_partial_kernel(
    const int* __restrict__ deg, int* __restrict__ blocksum)
{
    __shared__ int red[256];
    int t = threadIdx.x;
    int i = blockIdx.x * 256 + t;
    red[t] = (i < N_NODES) ? deg[i] : 0;
    __syncthreads();
    #pragma unroll
    for (int off = 128; off; off >>= 1) {
        if (t < off) red[t] += red[t + off];
        __syncthreads();
    }
    if (t == 0) blocksum[blockIdx.x] = red[0];
}

// ---------------------------------------------------------------------------
// K2b: every block scans the 196 block sums in LDS (redundant, cheap), then
// in-block exclusive scan of deg -> rowptr, cursor.
// ---------------------------------------------------------------------------
__global__ __launch_bounds__(256) void scan_final_kernel(
    const int* __restrict__ deg, const int* __restrict__ blocksum,
    int* __restrict__ rowptr, int* __restrict__ cursor)
{
    __shared__ int bs[256];
    __shared__ int s[256];
    int t = threadIdx.x;

    bs[t] = (t < SCAN_NBLK) ? blocksum[t] : 0;
    __syncthreads();
    for (int off = 1; off < 256; off <<= 1) {
        int v = (t >= off) ? bs[t - off] : 0;
        __syncthreads();
        bs[t] += v;
        __syncthreads();
    }
    int blockoff = (blockIdx.x == 0) ? 0 : bs[blockIdx.x - 1];

    int i = blockIdx.x * 256 + t;
    int v = (i < N_NODES) ? deg[i] : 0;
    s[t] = v;
    __syncthreads();
    for (int off = 1; off < 256; off <<= 1) {
        int u = (t >= off) ? s[t - off] : 0;
        __syncthreads();
        s[t] += u;
        __syncthreads();
    }
    int excl = s[t] - v + blockoff;
    if (i < N_NODES) {
        rowptr[i] = excl;
        cursor[i] = excl;
        if (i == N_NODES - 1) rowptr[N_NODES] = excl + v;
    }
}

// ---------------------------------------------------------------------------
// K3: scatter src ids into CSR slots (counting sort by dst)
// ---------------------------------------------------------------------------
__global__ __launch_bounds__(256) void csr_scatter_kernel(
    const int* __restrict__ src, const int* __restrict__ dst,
    int* __restrict__ cursor, int* __restrict__ csr_src)
{
    int e = blockIdx.x * blockDim.x + threadIdx.x;
    if (e >= N_EDGES) return;
    int pos = atomicAdd(&cursor[dst[e]], 1);
    csr_src[pos] = src[e];
}

// ---------------------------------------------------------------------------
// K4: per-dst-node fused dot + online softmax + weighted aggregate (fp32).
// r16-proven best: 4-deep unroll, 1 node per 32-lane group, 8 nodes/block,
// no block barrier. bf16 output (the conversion the GEMM needed anyway).
// Four ILP variants (8-deep, VGPR-capped, 2-node interleave) all measured
// neutral-to-worse: the kernel is L2-request-rate bound (~4M lines/pass),
// so request count, not ILP, sets the floor (~41us).
// ---------------------------------------------------------------------------
__global__ __launch_bounds__(256) void node_aggregate_kernel(
    const float* __restrict__ emb,
    const int* __restrict__ rowptr,
    const int* __restrict__ csr_src,
    ushort* __restrict__ neigh_bf)
{
    int node = blockIdx.x * 8 + (threadIdx.x >> 5);
    int lane = threadIdx.x & 31;
    if (node >= N_NODES) return;

    int beg = rowptr[node];
    int end = rowptr[node + 1];

    const float4 b = *((const float4*)(emb + (size_t)node * H_DIM) + lane);

    float m = -INFINITY;
    float denom = 0.f;
    float4 acc = {0.f, 0.f, 0.f, 0.f};

    int e = beg;
    for (; e + 4 <= end; e += 4) {
        float4 a[4];
        float  p[4];
        #pragma unroll
        for (int u = 0; u < 4; ++u) {
            int s = csr_src[e + u];
            a[u] = *((const float4*)(emb + (size_t)s * H_DIM) + lane);
        }
        #pragma unroll
        for (int u = 0; u < 4; ++u)
            p[u] = a[u].x * b.x + a[u].y * b.y + a[u].z * b.z + a[u].w * b.w;
        #pragma unroll
        for (int off = 16; off; off >>= 1) {
            #pragma unroll
            for (int u = 0; u < 4; ++u)
                p[u] += __shfl_xor(p[u], off);
        }
        float mn = fmaxf(fmaxf(fmaxf(p[0], p[1]), fmaxf(p[2], p[3])), m);
        float corr = __expf(m - mn);      // first iter: exp(-inf)=0
        float w[4];
        #pragma unroll
        for (int u = 0; u < 4; ++u) w[u] = __expf(p[u] - mn);
        denom = denom * corr + w[0] + w[1] + w[2] + w[3];
        acc.x = acc.x * corr + a[0].x*w[0] + a[1].x*w[1] + a[2].x*w[2] + a[3].x*w[3];
        acc.y = acc.y * corr + a[0].y*w[0] + a[1].y*w[1] + a[2].y*w[2] + a[3].y*w[3];
        acc.z = acc.z * corr + a[0].z*w[0] + a[1].z*w[1] + a[2].z*w[2] + a[3].z*w[3];
        acc.w = acc.w * corr + a[0].w*w[0] + a[1].w*w[1] + a[2].w*w[2] + a[3].w*w[3];
        m = mn;
    }
    for (; e < end; ++e) {
        int s = csr_src[e];
        float4 a = *((const float4*)(emb + (size_t)s * H_DIM) + lane);
        float p = a.x * b.x + a.y * b.y + a.z * b.z + a.w * b.w;
        #pragma unroll
        for (int off = 16; off; off >>= 1)
            p += __shfl_xor(p, off);
        float mn   = fmaxf(m, p);
        float corr = __expf(m - mn);
        float w    = __expf(p - mn);
        denom = denom * corr + w;
        acc.x = acc.x * corr + a.x * w;
        acc.y = acc.y * corr + a.y * w;
        acc.z = acc.z * corr + a.z * w;
        acc.w = acc.w * corr + a.w * w;
        m = mn;
    }

    float inv = (end > beg) ? (1.0f / denom) : 0.f;
    unsigned lo = (unsigned)f2bf(acc.x * inv) | ((unsigned)f2bf(acc.y * inv) << 16);
    unsigned hi = (unsigned)f2bf(acc.z * inv) | ((unsigned)f2bf(acc.w * inv) << 16);
    uint2 pk; pk.x = lo; pk.y = hi;
    *((uint2*)(neigh_bf + (size_t)node * H_DIM) + lane) = pk;
}

// ---------------------------------------------------------------------------
// K5: h = neigh_bf @ W via MFMA, NO data LDS (r16-proven): A-fragments from
// global bf16 neigh (16B contiguous per lane), B-fragments from L2-hot wt.
// 9 KB stats LDS only -> high occupancy, no staging barrier.
// Wave w -> rows (w>>1)*16, cols (w&1)*64; 4 col-tiles x 4 k-steps.
// C/D layout (m89): col=lane&15, row=(lane>>4)*4+reg.
// ---------------------------------------------------------------------------
__global__ __launch_bounds__(256) void gemm_stats_kernel(
    const ushort* __restrict__ neigh_bf,
    const ushort* __restrict__ wt,
    float* __restrict__ h,
    float* __restrict__ partial)
{
    __shared__ float red_s[128 * 9];
    __shared__ float red_q[128 * 9];

    int t  = threadIdx.x;
    int r0 = blockIdx.x * 32;

    int w      = t >> 6;
    int lane64 = t & 63;
    int rbase  = (w >> 1) * 16;
    int c0     = (w & 1) * 64;
    int l15    = lane64 & 15;
    int kgrp   = lane64 >> 4;
    int grow   = r0 + rbase + l15;
    int k0l    = kgrp * 8;

    floatx4 acc4[4] = {{0.f,0.f,0.f,0.f},{0.f,0.f,0.f,0.f},
                       {0.f,0.f,0.f,0.f},{0.f,0.f,0.f,0.f}};

    #pragma unroll
    for (int ks = 0; ks < 4; ++ks) {
        int k0 = ks * 32 + k0l;
        short8 af = {0,0,0,0,0,0,0,0};
        if (grow < N_NODES)
            af = *(const short8*)(neigh_bf + (size_t)grow * H_DIM + k0);
        #pragma unroll
        for (int ct = 0; ct < 4; ++ct) {
            int col = c0 + ct * 16 + l15;
            short8 bf = *(const short8*)(wt + (size_t)col * 128 + k0);
            acc4[ct] = __builtin_amdgcn_mfma_f32_16x16x32_bf16(af, bf, acc4[ct], 0, 0, 0);
        }
    }

    int contrib = (w >> 1) * 4 + kgrp;
    #pragma unroll
    for (int ct = 0; ct < 4; ++ct) {
        int col = c0 + ct * 16 + l15;
        float ps = 0.f, pq = 0.f;
        #pragma unroll
        for (int reg = 0; reg < 4; ++reg) {
            float v = acc4[ct][reg];
            int gr = r0 + rbase + kgrp * 4 + reg;
            if (gr < N_NODES) h[(size_t)gr * H_DIM + col] = v;
            ps += v;
            pq += v * v;
        }
        red_s[col * 9 + contrib] = ps;
        red_q[col * 9 + contrib] = pq;
    }
    __syncthreads();

    float s = 0.f;
    if (t < 128) {
        #pragma unroll
        for (int q = 0; q < 8; ++q) s += red_s[t * 9 + q];
    } else {
        #pragma unroll
        for (int q = 0; q < 8; ++q) s += red_q[(t - 128) * 9 + q];
    }
    partial[(size_t)blockIdx.x * 256 + t] = s;
}

// ---------------------------------------------------------------------------
// K6: stage-1 partial reduction: 64 blocks sum 1563 rows -> partial2[64][256]
// ---------------------------------------------------------------------------
__global__ __launch_bounds__(256) void reduce_partials_kernel(
    const float* __restrict__ partial, float* __restrict__ partial2)
{
    int t = threadIdx.x;
    int g = blockIdx.x;
    float s = 0.f;
    for (int b = g; b < GEMM_GRID; b += RED_NBLK)
        s += partial[(size_t)b * 256 + t];
    partial2[(size_t)g * 256 + t] = s;
}

// ---------------------------------------------------------------------------
// K7: each of 512 blocks redundantly folds the 64KB L2-hot partial2 into
// scale/shift in LDS, then grid-strides normalize+tanh over h in place.
// ---------------------------------------------------------------------------
__global__ __launch_bounds__(256) void bn_fold_tanh_kernel(
    const float* __restrict__ partial2,
    const float* __restrict__ gamma,
    const float* __restrict__ beta,
    float* __restrict__ h)
{
    __shared__ float tot[256];
    __shared__ float sc_s[128];
    __shared__ float sh_s[128];
    int t = threadIdx.x;

    float s = 0.f;
    #pragma unroll 8
    for (int b = 0; b < RED_NBLK; ++b)
        s += partial2[b * 256 + t];
    tot[t] = s;
    __syncthreads();
    if (t < 128) {
        float cs = tot[t];
        float cq = tot[t + 128];
        const float invN = 1.0f / (float)N_NODES;
        float mu  = cs * invN;
        float var = cq * invN - mu * mu;   // biased, matches jnp.var
        float sc  = gamma[t] * rsqrtf(var + BN_EPS);
        sc_s[t] = sc;
        sh_s[t] = beta[t] - mu * sc;
    }
    __syncthreads();

    const size_t total4 = (size_t)N_NODES * H_DIM / 4;
    for (size_t i = (size_t)blockIdx.x * 256 + t; i < total4;
         i += (size_t)gridDim.x * 256) {
        size_t idx4 = i * 4;
        int c = (int)(idx4 & (H_DIM - 1));
        float4 v = *(float4*)(h + idx4);
        v.x = tanhf(v.x * sc_s[c + 0] + sh_s[c + 0]);
        v.y = tanhf(v.y * sc_s[c + 1] + sh_s[c + 1]);
        v.z = tanhf(v.z * sc_s[c + 2] + sh_s[c + 2]);
        v.w = tanhf(v.w * sc_s[c + 3] + sh_s[c + 3]);
        *(float4*)(h + idx4) = v;
    }
}

// ---------------------------------------------------------------------------
extern "C" void kernel_launch(void* const* d_in, const int* in_sizes, int n_in,
                              void* d_out, int out_size, void* d_ws, size_t ws_size,
                              hipStream_t stream)
{
    const float* ent_emb = (const float*)d_in[0];
    const float* neigh_w = (const float*)d_in[1];
    const float* gamma   = (const float*)d_in[2];
    const float* beta    = (const float*)d_in[3];
    const int*   src     = (const int*)d_in[4];
    const int*   dst     = (const int*)d_in[5];
    float* out = (float*)d_out;

    int*    deg      = (int*)d_ws;                                   // 50000
    int*    rowptr   = deg + N_NODES;                                // 50001
    int*    cursor   = rowptr + N_NODES + 1;                         // 50000
    int*    csr_src  = cursor + N_NODES;                             // 500000
    int*    blocksum = csr_src + N_EDGES;                            // 196
    float*  partial  = (float*)(blocksum + SCAN_NBLK);               // 1563*256
    float*  partial2 = partial + (size_t)GEMM_GRID * 256;            // 64*256
    ushort* wt       = (ushort*)(partial2 + (size_t)RED_NBLK * 256); // 16384
    ushort* neigh_bf = wt + H_DIM * H_DIM;                           // 6.4M

    zero_deg_kernel<<<(N_NODES / 4 + 255) / 256, 256, 0, stream>>>(deg);

    // CSR build (counting sort by dst) + W->bf16^T fused into hist
    hist_cvt_kernel<<<(N_EDGES + 255) / 256, 256, 0, stream>>>(dst, deg, neigh_w, wt);
    scan_partial_kernel<<<SCAN_NBLK, 256, 0, stream>>>(deg, blocksum);
    scan_final_kernel<<<SCAN_NBLK, 256, 0, stream>>>(deg, blocksum, rowptr, cursor);
    csr_scatter_kernel<<<(N_EDGES + 255) / 256, 256, 0, stream>>>(src, dst, cursor, csr_src);

    // gather + online softmax + aggregate -> bf16 neigh
    node_aggregate_kernel<<<(N_NODES + 7) / 8, 256, 0, stream>>>(
        ent_emb, rowptr, csr_src, neigh_bf);

    // LDS-free MFMA GEMM: h = neigh_bf @ W + column partials
    gemm_stats_kernel<<<GEMM_GRID, 256, 0, stream>>>(neigh_bf, wt, out, partial);

    // hierarchical BN stats fold + normalize + tanh
    reduce_partials_kernel<<<RED_NBLK, 256, 0, stream>>>(partial, partial2);
    bn_fold_tanh_kernel<<<512, 256, 0, stream>>>(partial2, gamma, beta, out);
}

// Round 21
// 142.326 us; speedup vs baseline: 6.1431x; 1.0558x over previous
//
#include <hip/hip_runtime.h>
#include <hip/hip_bf16.h>
#include <math.h>

#define N_NODES 50000
#define N_EDGES 500000
#define H_DIM   128
#define BN_EPS  1e-5f
#define GEMM_GRID ((N_NODES + 31) / 32)     // 1563: 32 rows per block
#define SCAN_NBLK ((N_NODES + 255) / 256)   // 196
#define RED_NBLK  64                        // partial2 rows (atomic targets)

typedef __attribute__((ext_vector_type(8))) short short8;
typedef __attribute__((ext_vector_type(4))) float floatx4;

__device__ __forceinline__ ushort f2bf(float x)   // fp32 -> bf16 RNE
{
    unsigned u = __float_as_uint(x);
    unsigned r = (u + 0x7FFFu + ((u >> 16) & 1u)) >> 16;
    return (ushort)r;
}

// ---------------------------------------------------------------------------
// K0: zero deg[] AND partial2[] with a proper grid (hipMemsetAsync's
// tiny-grid fill kernel costs ~40us on first touch; this is ~1.5us).
// partial2 must start at 0: gemm_stats atomically accumulates into it.
// ---------------------------------------------------------------------------
__global__ __launch_bounds__(256) void zero_kernel(
    int* __restrict__ deg, float* __restrict__ partial2)
{
    int i = blockIdx.x * 256 + threadIdx.x;
    int i4 = i * 4;
    if (i4 + 3 < N_NODES) {
        *(int4*)(deg + i4) = make_int4(0, 0, 0, 0);
    } else {
        for (int k = i4; k < N_NODES; ++k) deg[k] = 0;
    }
    if (i < RED_NBLK * 256 / 4) {
        float4 z = {0.f, 0.f, 0.f, 0.f};
        *(float4*)(partial2 + i * 4) = z;
    }
}

// ---------------------------------------------------------------------------
// K1: histogram of dst -> deg[]  (+ fused W fp32[k][c] -> bf16 wt[c][k])
// ---------------------------------------------------------------------------
__global__ __launch_bounds__(256) void hist_cvt_kernel(
    const int* __restrict__ dst, int* __restrict__ deg,
    const float* __restrict__ W, ushort* __restrict__ wt)
{
    int e = blockIdx.x * blockDim.x + threadIdx.x;
    if (e < N_EDGES) atomicAdd(&deg[dst[e]], 1);
    if (e < H_DIM * H_DIM) {
        int k = e >> 7, c = e & 127;
        wt[c * 128 + k] = f2bf(W[e]);
    }
}

// ---------------------------------------------------------------------------
// K2a: per-block sums of deg (196 blocks x 256)
// ---------------------------------------------------------------------------
__global__ __launch_bounds__(256) void scan_partial_kernel(
    const int* __restrict__ deg, int* __restrict__ blocksum)
{
    __shared__ int red[256];
    int t = threadIdx.x;
    int i = blockIdx.x * 256 + t;
    red[t] = (i < N_NODES) ? deg[i] : 0;
    __syncthreads();
    #pragma unroll
    for (int off = 128; off; off >>= 1) {
        if (t < off) red[t] += red[t + off];
        __syncthreads();
    }
    if (t == 0) blocksum[blockIdx.x] = red[0];
}

// ---------------------------------------------------------------------------
// K2b: every block scans the 196 block sums in LDS (redundant, cheap), then
// in-block exclusive scan of deg -> rowptr, cursor.
// ---------------------------------------------------------------------------
__global__ __launch_bounds__(256) void scan_final_kernel(
    const int* __restrict__ deg, const int* __restrict__ blocksum,
    int* __restrict__ rowptr, int* __restrict__ cursor)
{
    __shared__ int bs[256];
    __shared__ int s[256];
    int t = threadIdx.x;

    bs[t] = (t < SCAN_NBLK) ? blocksum[t] : 0;
    __syncthreads();
    for (int off = 1; off < 256; off <<= 1) {
        int v = (t >= off) ? bs[t - off] : 0;
        __syncthreads();
        bs[t] += v;
        __syncthreads();
    }
    int blockoff = (blockIdx.x == 0) ? 0 : bs[blockIdx.x - 1];

    int i = blockIdx.x * 256 + t;
    int v = (i < N_NODES) ? deg[i] : 0;
    s[t] = v;
    __syncthreads();
    for (int off = 1; off < 256; off <<= 1) {
        int u = (t >= off) ? s[t - off] : 0;
        __syncthreads();
        s[t] += u;
        __syncthreads();
    }
    int excl = s[t] - v + blockoff;
    if (i < N_NODES) {
        rowptr[i] = excl;
        cursor[i] = excl;
        if (i == N_NODES - 1) rowptr[N_NODES] = excl + v;
    }
}

// ---------------------------------------------------------------------------
// K3: scatter src ids into CSR slots (counting sort by dst)
// ---------------------------------------------------------------------------
__global__ __launch_bounds__(256) void csr_scatter_kernel(
    const int* __restrict__ src, const int* __restrict__ dst,
    int* __restrict__ cursor, int* __restrict__ csr_src)
{
    int e = blockIdx.x * blockDim.x + threadIdx.x;
    if (e >= N_EDGES) return;
    int pos = atomicAdd(&cursor[dst[e]], 1);
    csr_src[pos] = src[e];
}

// ---------------------------------------------------------------------------
// K4: per-dst-node fused dot + online softmax + weighted aggregate (fp32).
// Proven best: 4-deep unroll, 1 node per 32-lane group, 8 nodes/block,
// no block barrier. bf16 output. Five ILP variants all neutral-to-worse:
// the kernel is L2/L3-service bound, request count sets the ~41us floor.
// ---------------------------------------------------------------------------
__global__ __launch_bounds__(256) void node_aggregate_kernel(
    const float* __restrict__ emb,
    const int* __restrict__ rowptr,
    const int* __restrict__ csr_src,
    ushort* __restrict__ neigh_bf)
{
    int node = blockIdx.x * 8 + (threadIdx.x >> 5);
    int lane = threadIdx.x & 31;
    if (node >= N_NODES) return;

    int beg = rowptr[node];
    int end = rowptr[node + 1];

    const float4 b = *((const float4*)(emb + (size_t)node * H_DIM) + lane);

    float m = -INFINITY;
    float denom = 0.f;
    float4 acc = {0.f, 0.f, 0.f, 0.f};

    int e = beg;
    for (; e + 4 <= end; e += 4) {
        float4 a[4];
        float  p[4];
        #pragma unroll
        for (int u = 0; u < 4; ++u) {
            int s = csr_src[e + u];
            a[u] = *((const float4*)(emb + (size_t)s * H_DIM) + lane);
        }
        #pragma unroll
        for (int u = 0; u < 4; ++u)
            p[u] = a[u].x * b.x + a[u].y * b.y + a[u].z * b.z + a[u].w * b.w;
        #pragma unroll
        for (int off = 16; off; off >>= 1) {
            #pragma unroll
            for (int u = 0; u < 4; ++u)
                p[u] += __shfl_xor(p[u], off);
        }
        float mn = fmaxf(fmaxf(fmaxf(p[0], p[1]), fmaxf(p[2], p[3])), m);
        float corr = __expf(m - mn);      // first iter: exp(-inf)=0
        float w[4];
        #pragma unroll
        for (int u = 0; u < 4; ++u) w[u] = __expf(p[u] - mn);
        denom = denom * corr + w[0] + w[1] + w[2] + w[3];
        acc.x = acc.x * corr + a[0].x*w[0] + a[1].x*w[1] + a[2].x*w[2] + a[3].x*w[3];
        acc.y = acc.y * corr + a[0].y*w[0] + a[1].y*w[1] + a[2].y*w[2] + a[3].y*w[3];
        acc.z = acc.z * corr + a[0].z*w[0] + a[1].z*w[1] + a[2].z*w[2] + a[3].z*w[3];
        acc.w = acc.w * corr + a[0].w*w[0] + a[1].w*w[1] + a[2].w*w[2] + a[3].w*w[3];
        m = mn;
    }
    for (; e < end; ++e) {
        int s = csr_src[e];
        float4 a = *((const float4*)(emb + (size_t)s * H_DIM) + lane);
        float p = a.x * b.x + a.y * b.y + a.z * b.z + a.w * b.w;
        #pragma unroll
        for (int off = 16; off; off >>= 1)
            p += __shfl_xor(p, off);
        float mn   = fmaxf(m, p);
        float corr = __expf(m - mn);
        float w    = __expf(p - mn);
        denom = denom * corr + w;
        acc.x = acc.x * corr + a.x * w;
        acc.y = acc.y * corr + a.y * w;
        acc.z = acc.z * corr + a.z * w;
        acc.w = acc.w * corr + a.w * w;
        m = mn;
    }

    float inv = (end > beg) ? (1.0f / denom) : 0.f;
    unsigned lo = (unsigned)f2bf(acc.x * inv) | ((unsigned)f2bf(acc.y * inv) << 16);
    unsigned hi = (unsigned)f2bf(acc.z * inv) | ((unsigned)f2bf(acc.w * inv) << 16);
    uint2 pk; pk.x = lo; pk.y = hi;
    *((uint2*)(neigh_bf + (size_t)node * H_DIM) + lane) = pk;
}

// ---------------------------------------------------------------------------
// K5: h = neigh_bf @ W via MFMA, NO data LDS: A-fragments from global bf16
// neigh, B-fragments from L2-hot wt. 9 KB stats LDS only.
// Column partials now accumulate DIRECTLY into partial2[bid&63][t] via one
// unsafeAtomicAdd per thread: 400k atomics over 16,384 addresses (~24
// serialized RMWs each — unlike r3's 1M-onto-16-lines storm). Removes the
// reduce_partials dispatch (+its launch gap).
// ---------------------------------------------------------------------------
__global__ __launch_bounds__(256) void gemm_stats_kernel(
    const ushort* __restrict__ neigh_bf,
    const ushort* __restrict__ wt,
    float* __restrict__ h,
    float* __restrict__ partial2)
{
    __shared__ float red_s[128 * 9];
    __shared__ float red_q[128 * 9];

    int t  = threadIdx.x;
    int r0 = blockIdx.x * 32;

    int w      = t >> 6;
    int lane64 = t & 63;
    int rbase  = (w >> 1) * 16;
    int c0     = (w & 1) * 64;
    int l15    = lane64 & 15;
    int kgrp   = lane64 >> 4;
    int grow   = r0 + rbase + l15;
    int k0l    = kgrp * 8;

    floatx4 acc4[4] = {{0.f,0.f,0.f,0.f},{0.f,0.f,0.f,0.f},
                       {0.f,0.f,0.f,0.f},{0.f,0.f,0.f,0.f}};

    #pragma unroll
    for (int ks = 0; ks < 4; ++ks) {
        int k0 = ks * 32 + k0l;
        short8 af = {0,0,0,0,0,0,0,0};
        if (grow < N_NODES)
            af = *(const short8*)(neigh_bf + (size_t)grow * H_DIM + k0);
        #pragma unroll
        for (int ct = 0; ct < 4; ++ct) {
            int col = c0 + ct * 16 + l15;
            short8 bf = *(const short8*)(wt + (size_t)col * 128 + k0);
            acc4[ct] = __builtin_amdgcn_mfma_f32_16x16x32_bf16(af, bf, acc4[ct], 0, 0, 0);
        }
    }

    int contrib = (w >> 1) * 4 + kgrp;
    #pragma unroll
    for (int ct = 0; ct < 4; ++ct) {
        int col = c0 + ct * 16 + l15;
        float ps = 0.f, pq = 0.f;
        #pragma unroll
        for (int reg = 0; reg < 4; ++reg) {
            float v = acc4[ct][reg];
            int gr = r0 + rbase + kgrp * 4 + reg;
            if (gr < N_NODES) h[(size_t)gr * H_DIM + col] = v;
            ps += v;
            pq += v * v;
        }
        red_s[col * 9 + contrib] = ps;
        red_q[col * 9 + contrib] = pq;
    }
    __syncthreads();

    float s = 0.f;
    if (t < 128) {
        #pragma unroll
        for (int q = 0; q < 8; ++q) s += red_s[t * 9 + q];
    } else {
        #pragma unroll
        for (int q = 0; q < 8; ++q) s += red_q[(t - 128) * 9 + q];
    }
    unsafeAtomicAdd(&partial2[(size_t)(blockIdx.x & (RED_NBLK - 1)) * 256 + t], s);
}

// ---------------------------------------------------------------------------
// K6: each of 512 blocks redundantly folds the 64KB L2-hot partial2 into
// scale/shift in LDS, then grid-strides normalize+tanh over h in place.
// ---------------------------------------------------------------------------
__global__ __launch_bounds__(256) void bn_fold_tanh_kernel(
    const float* __restrict__ partial2,
    const float* __restrict__ gamma,
    const float* __restrict__ beta,
    float* __restrict__ h)
{
    __shared__ float tot[256];
    __shared__ float sc_s[128];
    __shared__ float sh_s[128];
    int t = threadIdx.x;

    float s = 0.f;
    #pragma unroll 8
    for (int b = 0; b < RED_NBLK; ++b)
        s += partial2[b * 256 + t];
    tot[t] = s;
    __syncthreads();
    if (t < 128) {
        float cs = tot[t];
        float cq = tot[t + 128];
        const float invN = 1.0f / (float)N_NODES;
        float mu  = cs * invN;
        float var = cq * invN - mu * mu;   // biased, matches jnp.var
        float sc  = gamma[t] * rsqrtf(var + BN_EPS);
        sc_s[t] = sc;
        sh_s[t] = beta[t] - mu * sc;
    }
    __syncthreads();

    const size_t total4 = (size_t)N_NODES * H_DIM / 4;
    for (size_t i = (size_t)blockIdx.x * 256 + t; i < total4;
         i += (size_t)gridDim.x * 256) {
        size_t idx4 = i * 4;
        int c = (int)(idx4 & (H_DIM - 1));
        float4 v = *(float4*)(h + idx4);
        v.x = tanhf(v.x * sc_s[c + 0] + sh_s[c + 0]);
        v.y = tanhf(v.y * sc_s[c + 1] + sh_s[c + 1]);
        v.z = tanhf(v.z * sc_s[c + 2] + sh_s[c + 2]);
        v.w = tanhf(v.w * sc_s[c + 3] + sh_s[c + 3]);
        *(float4*)(h + idx4) = v;
    }
}

// ---------------------------------------------------------------------------
extern "C" void kernel_launch(void* const* d_in, const int* in_sizes, int n_in,
                              void* d_out, int out_size, void* d_ws, size_t ws_size,
                              hipStream_t stream)
{
    const float* ent_emb = (const float*)d_in[0];
    const float* neigh_w = (const float*)d_in[1];
    const float* gamma   = (const float*)d_in[2];
    const float* beta    = (const float*)d_in[3];
    const int*   src     = (const int*)d_in[4];
    const int*   dst     = (const int*)d_in[5];
    float* out = (float*)d_out;

    int*    deg      = (int*)d_ws;                                   // 50000
    int*    rowptr   = deg + N_NODES;                                // 50001
    int*    cursor   = rowptr + N_NODES + 1;                         // 50000
    int*    csr_src  = cursor + N_NODES;                             // 500000
    int*    blocksum = csr_src + N_EDGES;                            // 196
    float*  partial2 = (float*)(blocksum + SCAN_NBLK);               // 64*256
    ushort* wt       = (ushort*)(partial2 + (size_t)RED_NBLK * 256); // 16384
    ushort* neigh_bf = wt + H_DIM * H_DIM;                           // 6.4M

    zero_kernel<<<(N_NODES / 4 + 255) / 256, 256, 0, stream>>>(deg, partial2);

    // CSR build (counting sort by dst) + W->bf16^T fused into hist
    hist_cvt_kernel<<<(N_EDGES + 255) / 256, 256, 0, stream>>>(dst, deg, neigh_w, wt);
    scan_partial_kernel<<<SCAN_NBLK, 256, 0, stream>>>(deg, blocksum);
    scan_final_kernel<<<SCAN_NBLK, 256, 0, stream>>>(deg, blocksum, rowptr, cursor);
    csr_scatter_kernel<<<(N_EDGES + 255) / 256, 256, 0, stream>>>(src, dst, cursor, csr_src);

    // gather + online softmax + aggregate -> bf16 neigh
    node_aggregate_kernel<<<(N_NODES + 7) / 8, 256, 0, stream>>>(
        ent_emb, rowptr, csr_src, neigh_bf);

    // LDS-free MFMA GEMM: h = neigh_bf @ W + atomic column partials
    gemm_stats_kernel<<<GEMM_GRID, 256, 0, stream>>>(neigh_bf, wt, out, partial2);

    // BN stats fold + normalize + tanh
    bn_fold_tanh_kernel<<<512, 256, 0, stream>>>(partial2, gamma, beta, out);
}